// Round 8
// baseline (312.607 us; speedup 1.0000x reference)
//
#include <hip/hip_runtime.h>

namespace {
constexpr int Bn = 16, Hn = 512, Wn = 512;
constexpr int HW  = Hn * Wn;        // 262144
constexpr int CHW = 8 * HW;         // 2097152
constexpr int NCOL = Bn * Wn;       // 8192 dice columns
constexpr int WALK = 4;             // rows walked per block (all 4 waves together)
constexpr int GX   = Hn / WALK;     // 128
constexpr int NBLK = GX * Bn;       // 2048 blocks
constexpr int FBLK = 32;            // finisher blocks; 32*64 slots == NBLK

constexpr float L2E  = 1.4426950408889634f;   // log2(e)
constexpr float LN2  = 0.6931471805599453f;
constexpr float CLMP = -144.26950408889634f;  // -100 / ln2 (clamp in log2 units)

__device__ __forceinline__ float frcp(float x) { return __builtin_amdgcn_rcpf(x); }
#if __has_builtin(__builtin_amdgcn_exp2f)
__device__ __forceinline__ float fexp2(float x) { return __builtin_amdgcn_exp2f(x); }
#else
__device__ __forceinline__ float fexp2(float x) { return exp2f(x); }
#endif
#if __has_builtin(__builtin_amdgcn_logf)
__device__ __forceinline__ float flog2(float x) { return __builtin_amdgcn_logf(x); }
#else
__device__ __forceinline__ float flog2(float x) { return log2f(x); }
#endif
} // namespace

// n[c](h,w) = sigmoid(c_map[c][h+DY[c]][w+DX[c]]), zero outside image.
// vote[i] = p[i] * n[7-i].  DX = {1,0,-1,1,-1,1,0,-1}, DY = {1,1,1,0,0,-1,-1,-1}.
// 2 px/lane: wave = 128-px quarter-row; block's 4 waves tile one full row and
// walk WALK rows together. Rolling sigma window in registers ([2] arrays).
// Log-of-product fusion throughout (log2 units; one xLN2 at bscal write):
//   conmap/px: log2( q0*q1*q2 * rcp(prod d_{3..7}) ) - sum_{bit=0} y   (1 log)
//   bimap/px:  log2( prod of 8 selected votes ), exact-zero votes excluded
//              and charged CLMP each                                   (1 log)

__global__ __launch_bounds__(256) void bicon_main(
    const float* __restrict__ c_map,
    const int*   __restrict__ target,
    const int*   __restrict__ con_target,
    float* __restrict__ col_i, float* __restrict__ col_j, float* __restrict__ col_x,
    double* __restrict__ bscal)
{
    const int tid  = threadIdx.x;        // 0..255
    const int lane = tid & 63;
    const int wv   = tid >> 6;           // 0..3 -> quarter-row
    const int b    = blockIdx.y;
    const int hstart = blockIdx.x * WALK;
    const int wq   = wv * 128 + lane * 2;    // this lane's 2 columns

    const float* cm = c_map      + (size_t)b * CHW;
    const int*   ct = con_target + (size_t)b * CHW;
    const int*   tg = target     + (size_t)b * HW;

    float s_con = 0.f, s_bi = 0.f, s_bce = 0.f, s_dec = 0.f;   // log2 units
    float ci[2] = {0, 0}, cj[2] = {0, 0}, cx[2] = {0, 0};

    auto sig2 = [&](const float2& v, float s[2]) {
        s[0] = frcp(1.f + fexp2(-v.x * L2E));
        s[1] = frcp(1.f + fexp2(-v.y * L2E));
    };

    // ---- carried window: sigma(ch0..2)@h, sigma(ch5..7)@h-1 ----
    float C0[2], C1[2], C2[2], P5[2], P6[2], P7[2];
    {
        const int pb = hstart * Wn + wq;
        sig2(*(const float2*)(cm + 0 * HW + pb), C0);
        sig2(*(const float2*)(cm + 1 * HW + pb), C1);
        sig2(*(const float2*)(cm + 2 * HW + pb), C2);
    }
    if (hstart > 0) {   // wave-uniform
        const int pb = (hstart - 1) * Wn + wq;
        sig2(*(const float2*)(cm + 5 * HW + pb), P5);
        sig2(*(const float2*)(cm + 6 * HW + pb), P6);
        sig2(*(const float2*)(cm + 7 * HW + pb), P7);
    } else {
#pragma unroll
        for (int k = 0; k < 2; ++k) { P5[k] = 0.f; P6[k] = 0.f; P7[k] = 0.f; }
    }

    const bool edR = (wq + 2 == Wn);     // wave 3, lane 63 only
    const bool edL = (wq == 0);          // wave 0, lane 0 only

    int h = hstart;
#pragma unroll 1
    for (int r = 0; r < WALK; ++r, ++h) {
        const int  base  = h * Wn + wq;
        const bool hasDn = (h + 1 < Hn);
        const bool hasUp = (h > 0);

        // ---- all independent loads first ----
        const float2 xa3 = *(const float2*)(cm + 3 * HW + base);
        const float2 xa4 = *(const float2*)(cm + 4 * HW + base);
        const float2 xa5 = *(const float2*)(cm + 5 * HW + base);
        const float2 xa6 = *(const float2*)(cm + 6 * HW + base);
        const float2 xa7 = *(const float2*)(cm + 7 * HW + base);
        const float2 xf0 = *(const float2*)(cm + 0 * HW + base + Wn);
        const float2 xf1 = *(const float2*)(cm + 1 * HW + base + Wn);
        const float2 xf2 = *(const float2*)(cm + 2 * HW + base + Wn);
        const float bx0 = cm[0 * HW + base + Wn + 2];   // ch0 @ (h+1, wq+2)
        const float bx2 = cm[2 * HW + base + Wn - 1];   // ch2 @ (h+1, wq-1)
        const float bx3 = cm[3 * HW + base + 2];        // ch3 @ (h,   wq+2)
        const float bx4 = cm[4 * HW + base - 1];        // ch4 @ (h,   wq-1)
        const float bx5 = cm[5 * HW + base - Wn + 2];   // ch5 @ (h-1, wq+2)
        const float bx7 = cm[7 * HW + base - Wn - 1];   // ch7 @ (h-1, wq-1)
        const int2  t2  = *(const int2*)(tg + base);

        unsigned lo = 0u;   // 8 channel bits x 2 px (byte per px)
#pragma unroll
        for (int c = 0; c < 8; ++c) {
            const int2 u = *(const int2*)(ct + c * HW + base);
            lo |= ((unsigned)u.x << c) | ((unsigned)u.y << (8 + c));
        }

        // ---- fresh centers ch3-7: sigma + conmap d-product accumulation ----
        float dp[2] = {1.f, 1.f};   // prod of d over ch3..7
        float ys[2] = {0.f, 0.f};   // sum of y where bit==0
        float c3[2], c4[2], c5[2], c6[2], c7[2];
        auto fresh = [&](int c, const float2& v, float s[2]) {
            const float xs[2] = {v.x, v.y};
#pragma unroll
            for (int k = 0; k < 2; ++k) {
                const float y = xs[k] * L2E;
                const float e = fexp2(-y);
                const float d = 1.f + e;
                s[k] = frcp(d);
                dp[k] *= d;
                ys[k] += ((lo >> (8 * k + c)) & 1u) ? 0.f : y;
            }
        };
        fresh(3, xa3, c3); fresh(4, xa4, c4); fresh(5, xa5, c5);
        fresh(6, xa6, c6); fresh(7, xa7, c7);

        // ---- conmap: one log per pixel ----
#pragma unroll
        for (int k = 0; k < 2; ++k) {
            const float q0 = ((lo >> (8 * k + 0)) & 1u) ? C0[k] : 1.f - C0[k];
            const float q1 = ((lo >> (8 * k + 1)) & 1u) ? C1[k] : 1.f - C1[k];
            const float q2 = ((lo >> (8 * k + 2)) & 1u) ? C2[k] : 1.f - C2[k];
            s_con += flog2(q0 * q1 * q2 * frcp(dp[k])) - ys[k];
        }

        // ---- next-row + boundary sigmas ----
        float F0[2], F1[2], F2[2];
        sig2(xf0, F0); sig2(xf1, F1); sig2(xf2, F2);
        const float s0b = frcp(1.f + fexp2(-bx0 * L2E));
        const float s2b = frcp(1.f + fexp2(-bx2 * L2E));
        const float s3b = frcp(1.f + fexp2(-bx3 * L2E));
        const float s4b = frcp(1.f + fexp2(-bx4 * L2E));
        const float s5b = frcp(1.f + fexp2(-bx5 * L2E));
        const float s7b = frcp(1.f + fexp2(-bx7 * L2E));

        // ---- neighbor arrays (masked shifts) ----
        float n0[2], n1[2], n2[2], n3[2], n4[2], n5[2], n6[2], n7[2];
        n0[0] = F0[1];  n3[0] = c3[1];  n5[0] = P5[1];
        n2[1] = F2[0];  n4[1] = c4[0];  n7[1] = P7[0];
        n0[1] = edR ? 0.f : s0b;  n3[1] = edR ? 0.f : s3b;  n5[1] = edR ? 0.f : s5b;
        n2[0] = edL ? 0.f : s2b;  n4[0] = edL ? 0.f : s4b;  n7[0] = edL ? 0.f : s7b;
#pragma unroll
        for (int k = 0; k < 2; ++k) {
            n1[k] = hasDn ? F1[k] : 0.f;
            n6[k] = hasUp ? P6[k] : 0.f;
            if (!hasDn) { n0[k] = 0.f; n2[k] = 0.f; }
            if (!hasUp) { n5[k] = 0.f; n7[k] = 0.f; }
        }

        // ---- votes: vote[i] = p[i]*n[7-i]; single product of 8 per px ----
        float vmax[2] = {0.f, 0.f}, vmin[2] = {2.f, 2.f};
        float pr[2]   = {1.f, 1.f};
        float zc[2]   = {0.f, 0.f};   // count of bit=1 exact-zero votes
        auto vote = [&](int i, const float p[2], const float n[2]) {
#pragma unroll
            for (int k = 0; k < 2; ++k) {
                const float v = p[k] * n[k];
                vmax[k] = fmaxf(vmax[k], v);
                vmin[k] = fminf(vmin[k], v);
                const bool bit = (lo >> (8 * k + i)) & 1u;
                const bool z   = bit && (v == 0.f);     // only from masked edges
                float sel = bit ? v : 1.f - v;
                sel = z ? 1.f : sel;
                zc[k] += z ? 1.f : 0.f;
                pr[k] *= sel;
            }
        };
        vote(0, C0, n7); vote(1, C1, n6); vote(2, C2, n5); vote(3, c3, n4);
        vote(4, c4, n3); vote(5, c5, n2); vote(6, c6, n1); vote(7, c7, n0);
#pragma unroll
        for (int k = 0; k < 2; ++k) { s_bi += flog2(pr[k]) + CLMP * zc[k]; }

        // ---- per-pixel tail ----
        const int tk[2] = {t2.x, t2.y};
#pragma unroll
        for (int k = 0; k < 2; ++k) {
            const float fm = vmax[k];
            s_bce += fmaxf(flog2(tk[k] ? fm : 1.f - fm), CLMP);
            const int sc = __popc((int)((lo >> (8 * k)) & 0xffu));
            s_dec += (sc > 0 && sc < 8) ? fmaxf(flog2(1.f - vmin[k]), CLMP) : 0.f;
            ci[k] += (float)tk[k];
            cj[k] += fm;
            cx[k] += tk[k] ? fm : 0.f;
        }

        // ---- rotate window ----
#pragma unroll
        for (int k = 0; k < 2; ++k) {
            C0[k] = F0[k]; C1[k] = F1[k]; C2[k] = F2[k];
            P5[k] = c5[k]; P6[k] = c6[k]; P7[k] = c7[k];
        }
    }

    // ---- dice partials: each thread owns its 2 columns exclusively ----
    {
        const int col = b * Wn + wq;
        atomicAdd(&col_i[col],     ci[0]);
        atomicAdd(&col_i[col + 1], ci[1]);
        atomicAdd(&col_j[col],     cj[0]);
        atomicAdd(&col_j[col + 1], cj[1]);
        atomicAdd(&col_x[col],     cx[0]);
        atomicAdd(&col_x[col + 1], cx[1]);
    }

    // ---- scalar sums: wave shuffle reduction -> tiny LDS -> bscal slot ----
#pragma unroll
    for (int off = 32; off > 0; off >>= 1) {
        s_con += __shfl_down(s_con, off);
        s_bi  += __shfl_down(s_bi,  off);
        s_bce += __shfl_down(s_bce, off);
        s_dec += __shfl_down(s_dec, off);
    }
    __shared__ float wred[4][4];
    if (lane == 0) {   // log2 -> ln conversion here
        wred[wv][0] = s_con * LN2; wred[wv][1] = s_bi * LN2;
        wred[wv][2] = s_bce * LN2; wred[wv][3] = s_dec * LN2;
    }
    __syncthreads();
    if (tid < 4) {
        bscal[((size_t)blockIdx.y * GX + blockIdx.x) * 4 + tid] =
            (double)(wred[0][tid] + wred[1][tid] + wred[2][tid] + wred[3][tid]);
    }
}

__global__ __launch_bounds__(256) void bicon_finish(
    const float* __restrict__ col_i,
    const float* __restrict__ col_j,
    const float* __restrict__ col_x,
    const double* __restrict__ bscal,
    float* __restrict__ out)
{
    const int tid = threadIdx.x;
    const int col = blockIdx.x * 256 + tid;      // exactly NCOL threads total

    double part;
    {
        const float fi = col_i[col], fj = col_j[col], fx = col_x[col];
        part = (1.0 - (2.0 * (double)fx + 0.001) /
                      ((double)fi + (double)fj + 0.001)) / 8192.0;
    }
    if (tid < 64) {   // 64 bscal slots per block: 32 blocks * 64 = 2048 = NBLK
        const int s = blockIdx.x * 64 + tid;
        const double c0 = bscal[s * 4 + 0], c1 = bscal[s * 4 + 1];
        const double c2 = bscal[s * 4 + 2], c3 = bscal[s * 4 + 3];
        part += -0.8 * c0 / 33554432.0 - 0.2 * c1 / 33554432.0
                - c2 / 4194304.0 - c3 / 4194304.0;
    }
#pragma unroll
    for (int off = 32; off > 0; off >>= 1) part += __shfl_down(part, off);
    __shared__ double red[4];
    if ((tid & 63) == 0) red[tid >> 6] = part;
    __syncthreads();
    if (tid == 0) atomicAdd(out, (float)(red[0] + red[1] + red[2] + red[3]));
}

extern "C" void kernel_launch(void* const* d_in, const int* in_sizes, int n_in,
                              void* d_out, int out_size, void* d_ws, size_t ws_size,
                              hipStream_t stream) {
    const float* c_map      = (const float*)d_in[0];
    const int*   target     = (const int*)d_in[1];
    const int*   con_target = (const int*)d_in[2];
    float* out = (float*)d_out;

    char* ws = (char*)d_ws;
    float*  col_i = (float*)ws;                               // 8192 floats
    float*  col_j = col_i + NCOL;
    float*  col_x = col_j + NCOL;
    double* bscal = (double*)(ws + 3 * NCOL * sizeof(float)); // 2048*4 doubles

    hipMemsetAsync(d_ws, 0, 3 * NCOL * sizeof(float), stream); // zero col tables
    hipMemsetAsync(d_out, 0, sizeof(float), stream);           // finisher atomics here

    dim3 grid(GX, Bn);       // 128 x 16 = 2048 blocks
    dim3 block(256);
    bicon_main<<<grid, block, 0, stream>>>(c_map, target, con_target,
                                           col_i, col_j, col_x, bscal);
    bicon_finish<<<FBLK, 256, 0, stream>>>(col_i, col_j, col_x, bscal, out);
}